// Round 3
// baseline (191.862 us; speedup 1.0000x reference)
//
#include <hip/hip_runtime.h>
#include <stdint.h>

#define S_LEN 1024
#define DM 1024
#define NH 16
#define DH 64
#define NB 4

typedef unsigned short u16;
typedef __attribute__((ext_vector_type(8))) short short8;
typedef __attribute__((ext_vector_type(4))) float f32x4;
typedef __attribute__((ext_vector_type(4))) unsigned int u32x4;

__device__ __forceinline__ u16 f2bf(float f) {
  union { float f; unsigned int u; } c;
  c.f = f;
  unsigned int u = c.u;
  return (u16)((u + 0x7fffu + ((u >> 16) & 1u)) >> 16);
}

// async global->LDS, 16B per lane. LDS dest must be wave-uniform-base + lane*16.
__device__ __forceinline__ void g2l16(const void* g, void* l) {
  __builtin_amdgcn_global_load_lds(
      (const __attribute__((address_space(1))) unsigned int*)(uintptr_t)g,
      (__attribute__((address_space(3))) unsigned int*)(uint32_t)(uintptr_t)l,
      16, 0, 0);
}

// ---------------------------------------------------------------------------
// Kernel 0: fp32 -> bf16 pre-convert of x, Wq, Wk, Wv, Er into workspace.
// ---------------------------------------------------------------------------
__global__ __launch_bounds__(256) void cvt_f32_bf16(
    const float* __restrict__ x, const float* __restrict__ Wq,
    const float* __restrict__ Wk, const float* __restrict__ Wv,
    const float* __restrict__ Er, u16* __restrict__ xb,
    u16* __restrict__ Wqb, u16* __restrict__ Wkb, u16* __restrict__ Wvb,
    u16* __restrict__ Erb) {
  const size_t f = ((size_t)blockIdx.x * 256 + threadIdx.x) * 8;
  const float* src;
  u16* dst;
  size_t off;
  if (f < 4194304) { src = x; dst = xb; off = f; }
  else if (f < 5242880) { src = Wq; dst = Wqb; off = f - 4194304; }
  else if (f < 6291456) { src = Wk; dst = Wkb; off = f - 5242880; }
  else if (f < 7340032) { src = Wv; dst = Wvb; off = f - 6291456; }
  else { src = Er; dst = Erb; off = f - 7340032; }
  const float4 a = *(const float4*)(src + off);
  const float4 b = *(const float4*)(src + off + 4);
  u16 o[8] = {f2bf(a.x), f2bf(a.y), f2bf(a.z), f2bf(a.w),
              f2bf(b.x), f2bf(b.y), f2bf(b.z), f2bf(b.w)};
  *(u32x4*)(dst + off) = *(const u32x4*)o;
}

// ---------------------------------------------------------------------------
// Kernel 1: fused QKV projection (bf16 in, bf16 out).
// z=0 -> Q [B,H,S,dh], z=1 -> K [B,H,S,dh], z=2 -> V transposed [B,H,dh,S]
// ---------------------------------------------------------------------------
__global__ __launch_bounds__(256) void qkv_gemm(
    const u16* __restrict__ x,
    const u16* __restrict__ Wq, const float* __restrict__ bq,
    const u16* __restrict__ Wk, const float* __restrict__ bk,
    const u16* __restrict__ Wv, const float* __restrict__ bv,
    u16* __restrict__ Qo, u16* __restrict__ Ko, u16* __restrict__ Vo) {
  __shared__ __attribute__((aligned(16))) u16 Al[128 * 32];
  __shared__ __attribute__((aligned(16))) u16 Bl[128 * 32];

  const int tid = threadIdx.x;
  const int lane = tid & 63;
  const int wave = tid >> 6;
  const int z = blockIdx.z;
  const u16* W = (z == 0) ? Wq : (z == 1) ? Wk : Wv;
  const float* bias = (z == 0) ? bq : (z == 1) ? bk : bv;

  const int m0 = blockIdx.y * 128;
  const int n0 = blockIdx.x * 128;

  f32x4 acc[4][4];
  const f32x4 fzero = {0.f, 0.f, 0.f, 0.f};
#pragma unroll
  for (int i = 0; i < 4; i++)
#pragma unroll
    for (int j = 0; j < 4; j++) acc[i][j] = fzero;

  const int srow = tid >> 2;
  const int schunk = tid & 3;
  const u16* gA = x + (size_t)(m0 + srow) * DM + schunk * 8;
  const u16* gB = W + (size_t)(n0 + srow) * DM + schunk * 8;

  const int fr = lane & 15;
  const int fq = lane >> 4;
  const int wr = (wave >> 1) * 64;
  const int wc = (wave & 1) * 64;

  for (int k = 0; k < DM; k += 32) {
    g2l16(gA + k, &Al[tid * 8]);
    g2l16(gA + (size_t)64 * DM + k, &Al[2048 + tid * 8]);
    g2l16(gB + k, &Bl[tid * 8]);
    g2l16(gB + (size_t)64 * DM + k, &Bl[2048 + tid * 8]);
    __syncthreads();
    short8 a[4], b[4];
#pragma unroll
    for (int i = 0; i < 4; i++)
      a[i] = *(const short8*)&Al[(wr + i * 16 + fr) * 32 + fq * 8];
#pragma unroll
    for (int j = 0; j < 4; j++)
      b[j] = *(const short8*)&Bl[(wc + j * 16 + fr) * 32 + fq * 8];
#pragma unroll
    for (int i = 0; i < 4; i++)
#pragma unroll
      for (int j = 0; j < 4; j++)
        acc[i][j] =
            __builtin_amdgcn_mfma_f32_16x16x32_bf16(a[i], b[j], acc[i][j], 0, 0, 0);
    __syncthreads();
  }

#pragma unroll
  for (int j = 0; j < 4; j++) {
    const int n = n0 + wc + j * 16 + fr;
    const float bsv = bias[n];
    const int h = n >> 6, d = n & (DH - 1);
#pragma unroll
    for (int i = 0; i < 4; i++) {
#pragma unroll
      for (int r = 0; r < 4; r++) {
        const int m = m0 + wr + i * 16 + fq * 4 + r;
        const int bb = m >> 10, s = m & (S_LEN - 1);
        const u16 o = f2bf(acc[i][j][r] + bsv);
        if (z == 2)
          Vo[((size_t)(bb * NH + h) * DH + d) * S_LEN + s] = o;  // V^T
        else if (z == 1)
          Ko[((size_t)(bb * NH + h) * S_LEN + s) * DH + d] = o;
        else
          Qo[((size_t)(bb * NH + h) * S_LEN + s) * DH + d] = o;
      }
    }
  }
}

// ---------------------------------------------------------------------------
// Kernel 2: causal flash attention with relative-position (skew) bias.
// Uniform-work restructure:
//  - 256-thread (4-wave) blocks; block (x,bh) sequentially processes 64-row
//    q-tiles x and 15-x -> every block does exactly 17 j-iters (no stragglers).
//  - K/V double-buffered in LDS via global_load_lds (prefetch next tile before
//    computing current; ONE __syncthreads per iter whose implicit vmcnt(0)
//    drains the async loads). 128B-stride rows, (row&7)<<4 XOR swizzle with
//    inverse-swizzled global source (rule: linear dest + pre-swizzled src).
//  - Er staged nowhere: fragments direct global->VGPR (L2-resident 128KB
//    table), with register carry of the f=4 fragment across j-iters.
//  - Diagonal tiles skip fully-masked t-subtiles (t > w).
// LDS = 40KB. One barrier per iter.
// ---------------------------------------------------------------------------
__device__ __forceinline__ f32x4 er_frag(const u16* __restrict__ Er, int e0,
                                         int fr, int fq, short8 aq0,
                                         short8 aq1) {
  int e = e0 + fr;
  e = (e > S_LEN - 1) ? (S_LEN - 1) : e;  // OOB rows are masked anyway
  const short8 b0 = *(const short8*)&Er[(size_t)e * DH + fq * 8];
  const short8 b1 = *(const short8*)&Er[(size_t)e * DH + 32 + fq * 8];
  f32x4 z = {0.f, 0.f, 0.f, 0.f};
  z = __builtin_amdgcn_mfma_f32_16x16x32_bf16(aq0, b0, z, 0, 0, 0);
  z = __builtin_amdgcn_mfma_f32_16x16x32_bf16(aq1, b1, z, 0, 0, 0);
  return z;
}

__global__ __launch_bounds__(256, 4) void attn(
    const u16* __restrict__ Q, const u16* __restrict__ K,
    const u16* __restrict__ Vt, const u16* __restrict__ Er,
    float* __restrict__ out) {
  __shared__ __attribute__((aligned(16))) u16 Kl[2][64 * 64];
  __shared__ __attribute__((aligned(16))) u16 Vl[2][64 * 64];
  __shared__ __attribute__((aligned(16))) u16 Pl[4][16 * 64];

  const int tid = threadIdx.x;
  const int lane = tid & 63;
  const int w = tid >> 6;  // wave 0..3
  const int bh = blockIdx.y;
  const int b = bh >> 4, h = bh & (NH - 1);
  const int x = blockIdx.x;  // 0..7 -> q-tiles x and 15-x

  const u16* Qb = Q + (size_t)bh * S_LEN * DH;
  const char* Kb = (const char*)(K + (size_t)bh * S_LEN * DH);
  const char* Vb = (const char*)(Vt + (size_t)bh * DH * S_LEN);
  u16* Pw = Pl[w];

  const int fr = lane & 15;
  const int fq = lane >> 4;
  const f32x4 fzero = {0.f, 0.f, 0.f, 0.f};

  const int r0 = tid >> 3;        // staging row 0..31
  const int ch = (tid & 7) * 16;  // staging byte chunk within 128B row

  // stage K/V tile j0 into buffer bf: LDS[row][c'] = G[row][c' ^ ((row&7)<<4)]
  auto stage = [&](int j0, int bf) {
#pragma unroll
    for (int q = 0; q < 2; q++) {
      const int row = q * 32 + r0;
      const int sw = ch ^ ((row & 7) << 4);
      g2l16(Kb + (size_t)(j0 + row) * 128 + sw,
            (char*)&Kl[bf][0] + row * 128 + ch);
      g2l16(Vb + (size_t)row * 2048 + j0 * 2 + sw,
            (char*)&Vl[bf][0] + row * 128 + ch);
    }
  };

  int buf = 0;
  stage(0, 0);
  __syncthreads();

  for (int half = 0; half < 2; half++) {
    const int a = half ? 15 - x : x;  // this half's 64-row q-tile
    const int jmax = a * 64;
    const int i0w = a * 64 + w * 16;  // wave's 16 q-rows

    const short8 aq0 = *(const short8*)&Qb[(size_t)(i0w + fr) * DH + fq * 8];
    const short8 aq1 =
        *(const short8*)&Qb[(size_t)(i0w + fr) * DH + 32 + fq * 8];

    float mrow[4], lrow[4];
    f32x4 accO[4];
#pragma unroll
    for (int r = 0; r < 4; r++) { mrow[r] = -3.0e38f; lrow[r] = 0.f; }
#pragma unroll
    for (int t = 0; t < 4; t++) accO[t] = fzero;

    f32x4 zzc = fzero;  // carried Er fragment (prev f=4 -> next f=0)

    for (int j0 = 0; j0 <= jmax; j0 += 64) {
      // ---- prefetch next K/V tile (or next half's j0=0) into other buffer
      const int nj = (j0 < jmax) ? (j0 + 64) : (half == 0 ? 0 : -1);
      if (nj >= 0) stage(nj, buf ^ 1);

      const int tmax = (j0 == jmax) ? w : 3;  // skip fully-masked t-subtiles
      const int eb = S_LEN - 16 - i0w + j0;   // Er band base for this wave

      // ---- S = Q K^T from swizzled LDS
      const int ksw = (fr & 7) << 4;
      const char* Kbase = (const char*)&Kl[buf][0];
      f32x4 sfr[4];
#pragma unroll
      for (int t = 0; t < 4; t++) sfr[t] = fzero;
      __builtin_amdgcn_s_setprio(1);
#pragma unroll
      for (int t = 0; t < 4; t++)
        if (t <= tmax) {
          const char* kr = Kbase + (t * 16 + fr) * 128;
          const short8 b0 = *(const short8*)(kr + ((fq * 16) ^ ksw));
          const short8 b1 = *(const short8*)(kr + ((64 + fq * 16) ^ ksw));
          f32x4 z = fzero;
          z = __builtin_amdgcn_mfma_f32_16x16x32_bf16(aq0, b0, z, 0, 0, 0);
          z = __builtin_amdgcn_mfma_f32_16x16x32_bf16(aq1, b1, z, 0, 0, 0);
          sfr[t] = z;
        }
      __builtin_amdgcn_s_setprio(0);

      // ---- banded QEr: frags direct from global; f=0 carried when j0>0
      f32x4 zz[5];
#pragma unroll
      for (int f = 0; f < 5; f++) zz[f] = fzero;
      if (j0 > 0) zz[0] = zzc;
      const int f0 = (j0 == 0) ? 0 : 1;
#pragma unroll
      for (int f = 0; f < 5; f++)
        if (f >= f0 && f <= tmax + 1)
          zz[f] = er_frag(Er, eb + f * 16, fr, fq, aq0, aq1);
      zzc = zz[4];

      // ---- in-register skew gather: rel[t][r] = band col (15-row+fr)+16t
      float p[4][4];
#pragma unroll
      for (int r = 0; r < 4; r++) {
        const int row = fq * 4 + r;
        const int c = 15 - row + fr;           // 0..30
        const int src = (fq << 4) | (c & 15);  // same row-group, lane c&15
        float sh[5];
#pragma unroll
        for (int f = 0; f < 5; f++) sh[f] = __shfl(zz[f][r], src);
#pragma unroll
        for (int t = 0; t < 4; t++) {
          const float rel = (c < 16) ? sh[t] : sh[t + 1];
          float sv = (sfr[t][r] + rel) * 0.125f;
          const int jj = j0 + t * 16 + fr;
          const int ii = i0w + row;
          if (jj > ii) sv = -3.0e38f;
          p[t][r] = sv;
        }
      }

      // ---- online softmax (rows live in 16-lane groups)
#pragma unroll
      for (int r = 0; r < 4; r++) {
        float rm = fmaxf(fmaxf(p[0][r], p[1][r]), fmaxf(p[2][r], p[3][r]));
#pragma unroll
        for (int off = 1; off < 16; off <<= 1)
          rm = fmaxf(rm, __shfl_xor(rm, off));
        const float mnew = fmaxf(mrow[r], rm);
        const float alpha = __expf(mrow[r] - mnew);
        mrow[r] = mnew;
        float rs = 0.f;
#pragma unroll
        for (int t = 0; t < 4; t++) {
          const float e = __expf(p[t][r] - mnew);
          p[t][r] = e;
          rs += e;
        }
#pragma unroll
        for (int off = 1; off < 16; off <<= 1) rs += __shfl_xor(rs, off);
        lrow[r] = lrow[r] * alpha + rs;
#pragma unroll
        for (int t = 0; t < 4; t++) accO[t][r] *= alpha;
      }

      // ---- P transpose, wave-private, XOR-swizzled (stride 64 u16):
      //      phys el = logical el ^ ((q_row>>2)<<4) on both sides
#pragma unroll
      for (int t = 0; t < 4; t++)
#pragma unroll
        for (int r = 0; r < 4; r++)
          Pw[(fq * 4 + r) * 64 + (((t ^ fq) << 4) + fr)] = f2bf(p[t][r]);
      __builtin_amdgcn_s_waitcnt(0xC07F);  // lgkmcnt(0): own writes visible

      const int rsw = (fr >> 2) << 4;
      const short8 ap0 = *(const short8*)&Pw[fr * 64 + ((fq * 8) ^ rsw)];
      const short8 ap1 = *(const short8*)&Pw[fr * 64 + ((32 + fq * 8) ^ rsw)];

      // ---- O += P V from swizzled LDS
      const char* Vbase = (const char*)&Vl[buf][0];
      __builtin_amdgcn_s_setprio(1);
#pragma unroll
      for (int t = 0; t < 4; t++) {
        const char* vr = Vbase + (t * 16 + fr) * 128;
        const short8 b0 = *(const short8*)(vr + ((fq * 16) ^ ksw));
        const short8 b1 = *(const short8*)(vr + ((64 + fq * 16) ^ ksw));
        accO[t] =
            __builtin_amdgcn_mfma_f32_16x16x32_bf16(ap0, b0, accO[t], 0, 0, 0);
        accO[t] =
            __builtin_amdgcn_mfma_f32_16x16x32_bf16(ap1, b1, accO[t], 0, 0, 0);
      }
      __builtin_amdgcn_s_setprio(0);

      __syncthreads();  // implicit vmcnt(0)+lgkmcnt(0): prefetch landed,
                        // everyone done with current buffers
      buf ^= 1;
    }

    // ---- epilogue for this half: O / l, write [B,S,D] fp32
#pragma unroll
    for (int r = 0; r < 4; r++) {
      const float inv = 1.f / lrow[r];
      const int s = i0w + fq * 4 + r;
#pragma unroll
      for (int t = 0; t < 4; t++) {
        const int d = t * 16 + fr;
        out[((size_t)b * S_LEN + s) * DM + h * DH + d] = accO[t][r] * inv;
      }
    }
  }
}

extern "C" void kernel_launch(void* const* d_in, const int* in_sizes, int n_in,
                              void* d_out, int out_size, void* d_ws, size_t ws_size,
                              hipStream_t stream) {
  const float* x = (const float*)d_in[0];
  const float* Wq = (const float*)d_in[1];
  const float* bq = (const float*)d_in[2];
  const float* Wk = (const float*)d_in[3];
  const float* bk = (const float*)d_in[4];
  const float* Wv = (const float*)d_in[5];
  const float* bv = (const float*)d_in[6];
  const float* Er = (const float*)d_in[7];
  float* out = (float*)d_out;

  const size_t per = (size_t)NB * NH * S_LEN * DH;  // 4M elems
  u16* Qw = (u16*)d_ws;
  u16* Kw = Qw + per;
  u16* Vw = Kw + per;
  u16* xb = Vw + per;
  u16* Wqb = xb + per;
  u16* Wkb = Wqb + (size_t)DM * DM;
  u16* Wvb = Wkb + (size_t)DM * DM;
  u16* Erb = Wvb + (size_t)DM * DM;

  cvt_f32_bf16<<<3616, 256, 0, stream>>>(x, Wq, Wk, Wv, Er, xb, Wqb, Wkb, Wvb,
                                         Erb);
  dim3 g1(DM / 128, (NB * S_LEN) / 128, 3);
  qkv_gemm<<<g1, dim3(256), 0, stream>>>(xb, Wqb, bq, Wkb, bk, Wvb, bv, Qw, Kw,
                                         Vw);
  dim3 g2(8, NB * NH);
  attn<<<g2, dim3(256), 0, stream>>>(Qw, Kw, Vw, Erb, out);
}

// Round 4
// 188.482 us; speedup vs baseline: 1.0179x; 1.0179x over previous
//
#include <hip/hip_runtime.h>
#include <stdint.h>

#define S_LEN 1024
#define DM 1024
#define NH 16
#define DH 64
#define NB 4

typedef unsigned short u16;
typedef __attribute__((ext_vector_type(8))) short short8;
typedef __attribute__((ext_vector_type(4))) float f32x4;
typedef __attribute__((ext_vector_type(4))) unsigned int u32x4;

__device__ __forceinline__ u16 f2bf(float f) {
  union { float f; unsigned int u; } c;
  c.f = f;
  unsigned int u = c.u;
  return (u16)((u + 0x7fffu + ((u >> 16) & 1u)) >> 16);
}

// async global->LDS, 16B per lane. LDS dest must be wave-uniform-base + lane*16.
__device__ __forceinline__ void g2l16(const void* g, void* l) {
  __builtin_amdgcn_global_load_lds(
      (const __attribute__((address_space(1))) unsigned int*)(uintptr_t)g,
      (__attribute__((address_space(3))) unsigned int*)(uint32_t)(uintptr_t)l,
      16, 0, 0);
}

// 16-lane-group allreduce on the VALU pipe (DPP), replacing ds_bpermute shfls:
// xor1 (quad_perm [1,0,3,2]) -> xor2 (quad_perm [2,3,0,1]) -> row_ror:4 ->
// row_ror:8. Rotate-allreduce is direction-agnostic; exec must be wave-uniform.
__device__ __forceinline__ float grp16_max(float v) {
  union { float f; int i; } c, o;
  c.f = v; o.i = __builtin_amdgcn_update_dpp(c.i, c.i, 0xB1, 0xF, 0xF, false);
  v = fmaxf(v, o.f);
  c.f = v; o.i = __builtin_amdgcn_update_dpp(c.i, c.i, 0x4E, 0xF, 0xF, false);
  v = fmaxf(v, o.f);
  c.f = v; o.i = __builtin_amdgcn_update_dpp(c.i, c.i, 0x124, 0xF, 0xF, false);
  v = fmaxf(v, o.f);
  c.f = v; o.i = __builtin_amdgcn_update_dpp(c.i, c.i, 0x128, 0xF, 0xF, false);
  v = fmaxf(v, o.f);
  return v;
}
__device__ __forceinline__ float grp16_sum(float v) {
  union { float f; int i; } c, o;
  c.f = v; o.i = __builtin_amdgcn_update_dpp(c.i, c.i, 0xB1, 0xF, 0xF, false);
  v += o.f;
  c.f = v; o.i = __builtin_amdgcn_update_dpp(c.i, c.i, 0x4E, 0xF, 0xF, false);
  v += o.f;
  c.f = v; o.i = __builtin_amdgcn_update_dpp(c.i, c.i, 0x124, 0xF, 0xF, false);
  v += o.f;
  c.f = v; o.i = __builtin_amdgcn_update_dpp(c.i, c.i, 0x128, 0xF, 0xF, false);
  v += o.f;
  return v;
}

// ---------------------------------------------------------------------------
// Kernel 0: fp32 -> bf16 pre-convert of x, Wq, Wk, Wv, Er into workspace.
// ---------------------------------------------------------------------------
__global__ __launch_bounds__(256) void cvt_f32_bf16(
    const float* __restrict__ x, const float* __restrict__ Wq,
    const float* __restrict__ Wk, const float* __restrict__ Wv,
    const float* __restrict__ Er, u16* __restrict__ xb,
    u16* __restrict__ Wqb, u16* __restrict__ Wkb, u16* __restrict__ Wvb,
    u16* __restrict__ Erb) {
  const size_t f = ((size_t)blockIdx.x * 256 + threadIdx.x) * 8;
  const float* src;
  u16* dst;
  size_t off;
  if (f < 4194304) { src = x; dst = xb; off = f; }
  else if (f < 5242880) { src = Wq; dst = Wqb; off = f - 4194304; }
  else if (f < 6291456) { src = Wk; dst = Wkb; off = f - 5242880; }
  else if (f < 7340032) { src = Wv; dst = Wvb; off = f - 6291456; }
  else { src = Er; dst = Erb; off = f - 7340032; }
  const float4 a = *(const float4*)(src + off);
  const float4 b = *(const float4*)(src + off + 4);
  u16 o[8] = {f2bf(a.x), f2bf(a.y), f2bf(a.z), f2bf(a.w),
              f2bf(b.x), f2bf(b.y), f2bf(b.z), f2bf(b.w)};
  *(u32x4*)(dst + off) = *(const u32x4*)o;
}

// ---------------------------------------------------------------------------
// Kernel 1: fused QKV projection (bf16 in, bf16 out).
// z=0 -> Q [B,H,S,dh], z=1 -> K [B,H,S,dh], z=2 -> V transposed [B,H,dh,S]
// ---------------------------------------------------------------------------
__global__ __launch_bounds__(256) void qkv_gemm(
    const u16* __restrict__ x,
    const u16* __restrict__ Wq, const float* __restrict__ bq,
    const u16* __restrict__ Wk, const float* __restrict__ bk,
    const u16* __restrict__ Wv, const float* __restrict__ bv,
    u16* __restrict__ Qo, u16* __restrict__ Ko, u16* __restrict__ Vo) {
  __shared__ __attribute__((aligned(16))) u16 Al[128 * 32];
  __shared__ __attribute__((aligned(16))) u16 Bl[128 * 32];

  const int tid = threadIdx.x;
  const int lane = tid & 63;
  const int wave = tid >> 6;
  const int z = blockIdx.z;
  const u16* W = (z == 0) ? Wq : (z == 1) ? Wk : Wv;
  const float* bias = (z == 0) ? bq : (z == 1) ? bk : bv;

  const int m0 = blockIdx.y * 128;
  const int n0 = blockIdx.x * 128;

  f32x4 acc[4][4];
  const f32x4 fzero = {0.f, 0.f, 0.f, 0.f};
#pragma unroll
  for (int i = 0; i < 4; i++)
#pragma unroll
    for (int j = 0; j < 4; j++) acc[i][j] = fzero;

  const int srow = tid >> 2;
  const int schunk = tid & 3;
  const u16* gA = x + (size_t)(m0 + srow) * DM + schunk * 8;
  const u16* gB = W + (size_t)(n0 + srow) * DM + schunk * 8;

  const int fr = lane & 15;
  const int fq = lane >> 4;
  const int wr = (wave >> 1) * 64;
  const int wc = (wave & 1) * 64;

  for (int k = 0; k < DM; k += 32) {
    g2l16(gA + k, &Al[tid * 8]);
    g2l16(gA + (size_t)64 * DM + k, &Al[2048 + tid * 8]);
    g2l16(gB + k, &Bl[tid * 8]);
    g2l16(gB + (size_t)64 * DM + k, &Bl[2048 + tid * 8]);
    __syncthreads();
    short8 a[4], b[4];
#pragma unroll
    for (int i = 0; i < 4; i++)
      a[i] = *(const short8*)&Al[(wr + i * 16 + fr) * 32 + fq * 8];
#pragma unroll
    for (int j = 0; j < 4; j++)
      b[j] = *(const short8*)&Bl[(wc + j * 16 + fr) * 32 + fq * 8];
#pragma unroll
    for (int i = 0; i < 4; i++)
#pragma unroll
      for (int j = 0; j < 4; j++)
        acc[i][j] =
            __builtin_amdgcn_mfma_f32_16x16x32_bf16(a[i], b[j], acc[i][j], 0, 0, 0);
    __syncthreads();
  }

#pragma unroll
  for (int j = 0; j < 4; j++) {
    const int n = n0 + wc + j * 16 + fr;
    const float bsv = bias[n];
    const int h = n >> 6, d = n & (DH - 1);
#pragma unroll
    for (int i = 0; i < 4; i++) {
#pragma unroll
      for (int r = 0; r < 4; r++) {
        const int m = m0 + wr + i * 16 + fq * 4 + r;
        const int bb = m >> 10, s = m & (S_LEN - 1);
        const u16 o = f2bf(acc[i][j][r] + bsv);
        if (z == 2)
          Vo[((size_t)(bb * NH + h) * DH + d) * S_LEN + s] = o;  // V^T
        else if (z == 1)
          Ko[((size_t)(bb * NH + h) * S_LEN + s) * DH + d] = o;
        else
          Qo[((size_t)(bb * NH + h) * S_LEN + s) * DH + d] = o;
      }
    }
  }
}

// ---------------------------------------------------------------------------
// Kernel 2: causal flash attention with relative-position (skew) bias.
// r2 skeleton (8-wave blocks, 128-row i-tiles, lockstep j-walk, heavy/light
// pairing -> L2 reuse + 16 waves/CU) with LDS-pipe pressure stripped:
//  - K/V: 128B swizzled rows, double-buffered, global_load_lds prefetch,
//    ONE __syncthreads per iter (implicit vmcnt(0) drains prefetch).
//  - Er: no LDS staging; fragments direct global->VGPR (L2-resident table)
//    with register carry of the f=4 fragment across j-iters.
//  - Softmax reductions on VALU via DPP (no ds_bpermute).
//  - Diagonal t-skip: wave w computes only t <= tmax on the last j-tile.
// LDS = 48KB, one barrier per iter.
// ---------------------------------------------------------------------------
__device__ __forceinline__ f32x4 er_frag(const u16* __restrict__ Er, int e0,
                                         int fr, int fq, short8 aq0,
                                         short8 aq1) {
  int e = e0 + fr;
  e = (e > S_LEN - 1) ? (S_LEN - 1) : e;  // OOB rows are masked anyway
  const short8 b0 = *(const short8*)&Er[(size_t)e * DH + fq * 8];
  const short8 b1 = *(const short8*)&Er[(size_t)e * DH + 32 + fq * 8];
  f32x4 z = {0.f, 0.f, 0.f, 0.f};
  z = __builtin_amdgcn_mfma_f32_16x16x32_bf16(aq0, b0, z, 0, 0, 0);
  z = __builtin_amdgcn_mfma_f32_16x16x32_bf16(aq1, b1, z, 0, 0, 0);
  return z;
}

__global__ __launch_bounds__(512, 4) void attn(
    const u16* __restrict__ Q, const u16* __restrict__ K,
    const u16* __restrict__ Vt, const u16* __restrict__ Er,
    float* __restrict__ out) {
  __shared__ __attribute__((aligned(16))) u16 Kl[2][64 * 64];
  __shared__ __attribute__((aligned(16))) u16 Vl[2][64 * 64];
  __shared__ __attribute__((aligned(16))) u16 Pl[8][16 * 64];

  const int tid = threadIdx.x;
  const int lane = tid & 63;
  const int w = tid >> 6;  // wave 0..7
  const int bh = blockIdx.y;
  const int b = bh >> 4, h = bh & (NH - 1);
  // pair heavy i-tiles with light ones across the 2 scheduling rounds
  const int it = (bh < 32) ? (int)blockIdx.x : 7 - (int)blockIdx.x;
  const int i0 = it * 128;
  const int jmax = i0 + 64;

  const u16* Qb = Q + (size_t)bh * S_LEN * DH;
  const char* Kb = (const char*)(K + (size_t)bh * S_LEN * DH);
  const char* Vb = (const char*)(Vt + (size_t)bh * DH * S_LEN);
  u16* Pw = Pl[w];

  const int fr = lane & 15;
  const int fq = lane >> 4;
  const f32x4 fzero = {0.f, 0.f, 0.f, 0.f};

  // staging: 512 threads cover 64 rows x 128B; source pre-swizzled so LDS
  // dest stays linear (global_load_lds constraint), read side applies XOR.
  const int r0 = tid >> 3;             // row 0..63
  const int ch = (tid & 7) * 16;       // byte chunk in 128B row
  const int sw = ch ^ ((r0 & 7) << 4);  // pre-swizzled source chunk

  auto stage = [&](int j0, int bf) {
    g2l16(Kb + (size_t)(j0 + r0) * 128 + sw,
          (char*)&Kl[bf][0] + r0 * 128 + ch);
    g2l16(Vb + (size_t)r0 * 2048 + j0 * 2 + sw,
          (char*)&Vl[bf][0] + r0 * 128 + ch);
  };

  const int i0w = i0 + w * 16;  // this wave's 16 q-rows
  const short8 aq0 = *(const short8*)&Qb[(size_t)(i0w + fr) * DH + fq * 8];
  const short8 aq1 = *(const short8*)&Qb[(size_t)(i0w + fr) * DH + 32 + fq * 8];

  float mrow[4], lrow[4];
  f32x4 accO[4];
#pragma unroll
  for (int r = 0; r < 4; r++) { mrow[r] = -3.0e38f; lrow[r] = 0.f; }
#pragma unroll
  for (int t = 0; t < 4; t++) accO[t] = fzero;

  f32x4 zzc = fzero;  // carried Er band fragment (prev f=4 -> next f=0)

  int buf = 0;
  stage(0, 0);
  __syncthreads();

  for (int j0 = 0; j0 <= jmax; j0 += 64) {
    // ---- prefetch next K/V tile into the other buffer
    if (j0 < jmax) stage(j0 + 64, buf ^ 1);

    // wave-uniform: highest unmasked t-subtile for this wave (neg => skip)
    int tmax = (i0w + 15 - j0) >> 4;
    if (tmax > 3) tmax = 3;

    if (tmax >= 0) {
      const int ksw = (fr & 7) << 4;
      const char* Kbase = (const char*)&Kl[buf][0];

      // ---- S = Q K^T from swizzled LDS
      f32x4 sfr[4];
#pragma unroll
      for (int t = 0; t < 4; t++) sfr[t] = fzero;
      __builtin_amdgcn_s_setprio(1);
#pragma unroll
      for (int t = 0; t < 4; t++)
        if (t <= tmax) {
          const char* kr = Kbase + (t * 16 + fr) * 128;
          const short8 b0 = *(const short8*)(kr + ((fq * 16) ^ ksw));
          const short8 b1 = *(const short8*)(kr + ((64 + fq * 16) ^ ksw));
          f32x4 z = fzero;
          z = __builtin_amdgcn_mfma_f32_16x16x32_bf16(aq0, b0, z, 0, 0, 0);
          z = __builtin_amdgcn_mfma_f32_16x16x32_bf16(aq1, b1, z, 0, 0, 0);
          sfr[t] = z;
        }
      __builtin_amdgcn_s_setprio(0);

      // ---- banded QEr: fragments direct from global; f=0 carried when j0>0
      const int eb = S_LEN - 16 - i0w + j0;  // Er band base (>= 0)
      f32x4 zz[5];
#pragma unroll
      for (int f = 0; f < 5; f++) zz[f] = fzero;
      const int f0 = (j0 == 0) ? 0 : 1;
#pragma unroll
      for (int f = 0; f < 5; f++)
        if (f >= f0 && f <= tmax + 1)
          zz[f] = er_frag(Er, eb + f * 16, fr, fq, aq0, aq1);
      if (j0 > 0) zz[0] = zzc;
      zzc = zz[4];

      // ---- in-register skew gather: rel[t][r] = band col (15-row+fr)+16t
      float p[4][4];
#pragma unroll
      for (int r = 0; r < 4; r++) {
        const int row = fq * 4 + r;
        const int c = 15 - row + fr;           // 0..30
        const int src = (fq << 4) | (c & 15);  // same row-group, lane c&15
        float sh[5];
#pragma unroll
        for (int f = 0; f < 5; f++) sh[f] = __shfl(zz[f][r], src);
#pragma unroll
        for (int t = 0; t < 4; t++) {
          const float rel = (c < 16) ? sh[t] : sh[t + 1];
          float sv = (sfr[t][r] + rel) * 0.125f;
          const int jj = j0 + t * 16 + fr;
          const int ii = i0w + row;
          if (jj > ii) sv = -3.0e38f;
          p[t][r] = sv;
        }
      }

      // ---- online softmax (rows live in 16-lane groups, DPP reduce)
#pragma unroll
      for (int r = 0; r < 4; r++) {
        float rm = fmaxf(fmaxf(p[0][r], p[1][r]), fmaxf(p[2][r], p[3][r]));
        rm = grp16_max(rm);
        const float mnew = fmaxf(mrow[r], rm);
        const float alpha = __expf(mrow[r] - mnew);
        mrow[r] = mnew;
        float rs = 0.f;
#pragma unroll
        for (int t = 0; t < 4; t++) {
          const float e = __expf(p[t][r] - mnew);
          p[t][r] = e;
          rs += e;
        }
        rs = grp16_sum(rs);
        lrow[r] = lrow[r] * alpha + rs;
#pragma unroll
        for (int t = 0; t < 4; t++) accO[t][r] *= alpha;
      }

      // ---- P transpose, wave-private, XOR-swizzled (stride 64 u16):
      //      phys el = logical el ^ ((q_row>>2)<<4) on both sides
#pragma unroll
      for (int t = 0; t < 4; t++)
#pragma unroll
        for (int r = 0; r < 4; r++)
          Pw[(fq * 4 + r) * 64 + (((t ^ fq) << 4) + fr)] = f2bf(p[t][r]);
      __builtin_amdgcn_s_waitcnt(0xC07F);  // lgkmcnt(0): own writes visible

      const int rsw = (fr >> 2) << 4;
      const short8 ap0 = *(const short8*)&Pw[fr * 64 + ((fq * 8) ^ rsw)];
      const short8 ap1 = *(const short8*)&Pw[fr * 64 + ((32 + fq * 8) ^ rsw)];

      // ---- O += P V from swizzled LDS
      const char* Vbase = (const char*)&Vl[buf][0];
      __builtin_amdgcn_s_setprio(1);
#pragma unroll
      for (int t = 0; t < 4; t++) {
        const char* vr = Vbase + (t * 16 + fr) * 128;
        const short8 b0 = *(const short8*)(vr + ((fq * 16) ^ ksw));
        const short8 b1 = *(const short8*)(vr + ((64 + fq * 16) ^ ksw));
        accO[t] =
            __builtin_amdgcn_mfma_f32_16x16x32_bf16(ap0, b0, accO[t], 0, 0, 0);
        accO[t] =
            __builtin_amdgcn_mfma_f32_16x16x32_bf16(ap1, b1, accO[t], 0, 0, 0);
      }
      __builtin_amdgcn_s_setprio(0);
    }

    __syncthreads();  // implicit vmcnt(0)+lgkmcnt(0): prefetch landed,
                      // everyone done with current buffers
    buf ^= 1;
  }

  // ---- epilogue: O / l, write [B,S,D] fp32
#pragma unroll
  for (int r = 0; r < 4; r++) {
    const float inv = 1.f / lrow[r];
    const int s = i0w + fq * 4 + r;
#pragma unroll
    for (int t = 0; t < 4; t++) {
      const int d = t * 16 + fr;
      out[((size_t)b * S_LEN + s) * DM + h * DH + d] = accO[t][r] * inv;
    }
  }
}

extern "C" void kernel_launch(void* const* d_in, const int* in_sizes, int n_in,
                              void* d_out, int out_size, void* d_ws, size_t ws_size,
                              hipStream_t stream) {
  const float* x = (const float*)d_in[0];
  const float* Wq = (const float*)d_in[1];
  const float* bq = (const float*)d_in[2];
  const float* Wk = (const float*)d_in[3];
  const float* bk = (const float*)d_in[4];
  const float* Wv = (const float*)d_in[5];
  const float* bv = (const float*)d_in[6];
  const float* Er = (const float*)d_in[7];
  float* out = (float*)d_out;

  const size_t per = (size_t)NB * NH * S_LEN * DH;  // 4M elems
  u16* Qw = (u16*)d_ws;
  u16* Kw = Qw + per;
  u16* Vw = Kw + per;
  u16* xb = Vw + per;
  u16* Wqb = xb + per;
  u16* Wkb = Wqb + (size_t)DM * DM;
  u16* Wvb = Wkb + (size_t)DM * DM;
  u16* Erb = Wvb + (size_t)DM * DM;

  cvt_f32_bf16<<<3616, 256, 0, stream>>>(x, Wq, Wk, Wv, Er, xb, Wqb, Wkb, Wvb,
                                         Erb);
  dim3 g1(DM / 128, (NB * S_LEN) / 128, 3);
  qkv_gemm<<<g1, dim3(256), 0, stream>>>(xb, Wqb, bq, Wkb, bk, Wvb, bv, Qw, Kw,
                                         Vw);
  dim3 g2(8, NB * NH);
  attn<<<g2, dim3(512), 0, stream>>>(Qw, Kw, Vw, Erb, out);
}

// Round 5
// 174.856 us; speedup vs baseline: 1.0973x; 1.0779x over previous
//
#include <hip/hip_runtime.h>
#include <stdint.h>

#define S_LEN 1024
#define DM 1024
#define NH 16
#define DH 64
#define NB 4

typedef unsigned short u16;
typedef __attribute__((ext_vector_type(8))) short short8;
typedef __attribute__((ext_vector_type(4))) float f32x4;
typedef __attribute__((ext_vector_type(4))) unsigned int u32x4;

__device__ __forceinline__ u16 f2bf(float f) {
  union { float f; unsigned int u; } c;
  c.f = f;
  unsigned int u = c.u;
  return (u16)((u + 0x7fffu + ((u >> 16) & 1u)) >> 16);
}

// async global->LDS, 16B per lane. LDS dest must be wave-uniform-base + lane*16.
__device__ __forceinline__ void g2l16(const void* g, void* l) {
  __builtin_amdgcn_global_load_lds(
      (const __attribute__((address_space(1))) unsigned int*)(uintptr_t)g,
      (__attribute__((address_space(3))) unsigned int*)(uint32_t)(uintptr_t)l,
      16, 0, 0);
}

// 16-lane-group allreduce on the VALU pipe (DPP): quad_perm xor1, xor2,
// row_ror:4, row_ror:8. Rotate-allreduce; exec must be wave-uniform.
__device__ __forceinline__ float grp16_max(float v) {
  union { float f; int i; } c, o;
  c.f = v; o.i = __builtin_amdgcn_update_dpp(c.i, c.i, 0xB1, 0xF, 0xF, false);
  v = fmaxf(v, o.f);
  c.f = v; o.i = __builtin_amdgcn_update_dpp(c.i, c.i, 0x4E, 0xF, 0xF, false);
  v = fmaxf(v, o.f);
  c.f = v; o.i = __builtin_amdgcn_update_dpp(c.i, c.i, 0x124, 0xF, 0xF, false);
  v = fmaxf(v, o.f);
  c.f = v; o.i = __builtin_amdgcn_update_dpp(c.i, c.i, 0x128, 0xF, 0xF, false);
  v = fmaxf(v, o.f);
  return v;
}
__device__ __forceinline__ float grp16_sum(float v) {
  union { float f; int i; } c, o;
  c.f = v; o.i = __builtin_amdgcn_update_dpp(c.i, c.i, 0xB1, 0xF, 0xF, false);
  v += o.f;
  c.f = v; o.i = __builtin_amdgcn_update_dpp(c.i, c.i, 0x4E, 0xF, 0xF, false);
  v += o.f;
  c.f = v; o.i = __builtin_amdgcn_update_dpp(c.i, c.i, 0x124, 0xF, 0xF, false);
  v += o.f;
  c.f = v; o.i = __builtin_amdgcn_update_dpp(c.i, c.i, 0x128, 0xF, 0xF, false);
  v += o.f;
  return v;
}

// ---------------------------------------------------------------------------
// Kernel 0: fp32 -> bf16 pre-convert of x, Wq, Wk, Wv, Er into workspace.
// ---------------------------------------------------------------------------
__global__ __launch_bounds__(256) void cvt_f32_bf16(
    const float* __restrict__ x, const float* __restrict__ Wq,
    const float* __restrict__ Wk, const float* __restrict__ Wv,
    const float* __restrict__ Er, u16* __restrict__ xb,
    u16* __restrict__ Wqb, u16* __restrict__ Wkb, u16* __restrict__ Wvb,
    u16* __restrict__ Erb) {
  const size_t f = ((size_t)blockIdx.x * 256 + threadIdx.x) * 8;
  const float* src;
  u16* dst;
  size_t off;
  if (f < 4194304) { src = x; dst = xb; off = f; }
  else if (f < 5242880) { src = Wq; dst = Wqb; off = f - 4194304; }
  else if (f < 6291456) { src = Wk; dst = Wkb; off = f - 5242880; }
  else if (f < 7340032) { src = Wv; dst = Wvb; off = f - 6291456; }
  else { src = Er; dst = Erb; off = f - 7340032; }
  const float4 a = *(const float4*)(src + off);
  const float4 b = *(const float4*)(src + off + 4);
  u16 o[8] = {f2bf(a.x), f2bf(a.y), f2bf(a.z), f2bf(a.w),
              f2bf(b.x), f2bf(b.y), f2bf(b.z), f2bf(b.w)};
  *(u32x4*)(dst + off) = *(const u32x4*)o;
}

// ---------------------------------------------------------------------------
// Kernel 1: fused QKV projection (bf16 in, bf16 out).
// z=0 -> Q [B,H,S,dh], z=1 -> K [B,H,S,dh], z=2 -> V transposed [B,H,dh,S]
// ---------------------------------------------------------------------------
__global__ __launch_bounds__(256) void qkv_gemm(
    const u16* __restrict__ x,
    const u16* __restrict__ Wq, const float* __restrict__ bq,
    const u16* __restrict__ Wk, const float* __restrict__ bk,
    const u16* __restrict__ Wv, const float* __restrict__ bv,
    u16* __restrict__ Qo, u16* __restrict__ Ko, u16* __restrict__ Vo) {
  __shared__ __attribute__((aligned(16))) u16 Al[128 * 32];
  __shared__ __attribute__((aligned(16))) u16 Bl[128 * 32];

  const int tid = threadIdx.x;
  const int lane = tid & 63;
  const int wave = tid >> 6;
  const int z = blockIdx.z;
  const u16* W = (z == 0) ? Wq : (z == 1) ? Wk : Wv;
  const float* bias = (z == 0) ? bq : (z == 1) ? bk : bv;

  const int m0 = blockIdx.y * 128;
  const int n0 = blockIdx.x * 128;

  f32x4 acc[4][4];
  const f32x4 fzero = {0.f, 0.f, 0.f, 0.f};
#pragma unroll
  for (int i = 0; i < 4; i++)
#pragma unroll
    for (int j = 0; j < 4; j++) acc[i][j] = fzero;

  const int srow = tid >> 2;
  const int schunk = tid & 3;
  const u16* gA = x + (size_t)(m0 + srow) * DM + schunk * 8;
  const u16* gB = W + (size_t)(n0 + srow) * DM + schunk * 8;

  const int fr = lane & 15;
  const int fq = lane >> 4;
  const int wr = (wave >> 1) * 64;
  const int wc = (wave & 1) * 64;

  for (int k = 0; k < DM; k += 32) {
    g2l16(gA + k, &Al[tid * 8]);
    g2l16(gA + (size_t)64 * DM + k, &Al[2048 + tid * 8]);
    g2l16(gB + k, &Bl[tid * 8]);
    g2l16(gB + (size_t)64 * DM + k, &Bl[2048 + tid * 8]);
    __syncthreads();
    short8 a[4], b[4];
#pragma unroll
    for (int i = 0; i < 4; i++)
      a[i] = *(const short8*)&Al[(wr + i * 16 + fr) * 32 + fq * 8];
#pragma unroll
    for (int j = 0; j < 4; j++)
      b[j] = *(const short8*)&Bl[(wc + j * 16 + fr) * 32 + fq * 8];
#pragma unroll
    for (int i = 0; i < 4; i++)
#pragma unroll
      for (int j = 0; j < 4; j++)
        acc[i][j] =
            __builtin_amdgcn_mfma_f32_16x16x32_bf16(a[i], b[j], acc[i][j], 0, 0, 0);
    __syncthreads();
  }

#pragma unroll
  for (int j = 0; j < 4; j++) {
    const int n = n0 + wc + j * 16 + fr;
    const float bsv = bias[n];
    const int h = n >> 6, d = n & (DH - 1);
#pragma unroll
    for (int i = 0; i < 4; i++) {
#pragma unroll
      for (int r = 0; r < 4; r++) {
        const int m = m0 + wr + i * 16 + fq * 4 + r;
        const int bb = m >> 10, s = m & (S_LEN - 1);
        const u16 o = f2bf(acc[i][j][r] + bsv);
        if (z == 2)
          Vo[((size_t)(bb * NH + h) * DH + d) * S_LEN + s] = o;  // V^T
        else if (z == 1)
          Ko[((size_t)(bb * NH + h) * S_LEN + s) * DH + d] = o;
        else
          Qo[((size_t)(bb * NH + h) * S_LEN + s) * DH + d] = o;
      }
    }
  }
}

// ---------------------------------------------------------------------------
// Kernel 2: causal flash attention with relative-position (skew) bias.
// Residency-first restructure:
//  - 1024 blocks x 4 waves (64-row q-tiles). LDS = 40KB exactly -> 4 blocks/CU
//    (4x40960 = 160KB pool): 4 independent barrier domains per CU so stage /
//    barrier stalls of one block overlap compute of the other three.
//  - it-swizzle (x + bh + ((bh>>4)<<2)) & 15: per-bh bijection keeps same-bh
//    blocks j-synced (L2 reuse of K/V tiles); gives each CU's 4 resident
//    blocks tiles ~{a,a+4,a+8,a+12} -> per-CU iters in [28,40] (vs [4,64]).
//  - Er in a mod-128 LDS ring (16KB): 128 rows staged at j0=0, 64 fresh rows
//    per later iter; all staging (K/V/El) via global_load_lds with
//    pre-swizzled source; reads use (row&7)<<4 XOR -> conflict-free.
//  - Register-carried Er f=4 -> next f=0; DPP softmax; swizzled P transpose;
//    every wave has work at every j-iter (no idle waves).
// ---------------------------------------------------------------------------
__global__ __launch_bounds__(256, 4) void attn(
    const u16* __restrict__ Q, const u16* __restrict__ K,
    const u16* __restrict__ Vt, const u16* __restrict__ Er,
    float* __restrict__ out) {
  __shared__ __attribute__((aligned(16))) u16 Kl[64 * 64];   // 8KB
  __shared__ __attribute__((aligned(16))) u16 Vl[64 * 64];   // 8KB
  __shared__ __attribute__((aligned(16))) u16 El[128 * 64];  // 16KB ring
  __shared__ __attribute__((aligned(16))) u16 Pl[4][16 * 64];  // 8KB

  const int tid = threadIdx.x;
  const int lane = tid & 63;
  const int w = tid >> 6;  // wave 0..3
  const int bh = blockIdx.y;
  const int b = bh >> 4, h = bh & (NH - 1);
  const int it = ((int)blockIdx.x + bh + ((bh >> 4) << 2)) & 15;
  const int i0 = it * 64;        // this block's 64 q-rows
  const int i0w = i0 + w * 16;   // this wave's 16 q-rows
  const int E0b = S_LEN - 64 - i0;  // Er window base at j0=0 (>=0, mult of 64)

  const u16* Qb = Q + (size_t)bh * S_LEN * DH;
  const char* Kb = (const char*)(K + (size_t)bh * S_LEN * DH);
  const char* Vb = (const char*)(Vt + (size_t)bh * DH * S_LEN);
  const char* Eb = (const char*)Er;
  u16* Pw = Pl[w];

  const int fr = lane & 15;
  const int fq = lane >> 4;
  const f32x4 fzero = {0.f, 0.f, 0.f, 0.f};

  // staging: 256 threads, 16B each -> 32 rows x 128B per pass.
  const int r8 = tid >> 3;        // 0..31
  const int ch = (tid & 7) * 16;  // byte chunk within 128B row

  // K/V tile j0 (64 rows x 128B, 2 passes each). Source pre-swizzled so the
  // linear LDS dest + swizzled read form the same involution (rule #21).
  auto stageKV = [&](int j0) {
#pragma unroll
    for (int p = 0; p < 2; p++) {
      const int row = p * 32 + r8;
      const int sw = ch ^ ((row & 7) << 4);
      g2l16(Kb + (size_t)(j0 + row) * 128 + sw, (char*)Kl + row * 128 + ch);
      g2l16(Vb + (size_t)row * 2048 + j0 * 2 + sw, (char*)Vl + row * 128 + ch);
    }
  };
  // Er rows [e0, e0+32*np) into ring slots e&127. e0 mult of 32; 8-row chunks
  // are 8-aligned so a wave's dest never straddles the 128-wrap.
  auto stageEl = [&](int e0, int np) {
    for (int p = 0; p < np; p++) {
      const int e = e0 + p * 32 + r8;
      const int slot = e & 127;
      const int ec = (e > S_LEN - 1) ? (S_LEN - 1) : e;  // masked anyway
      const int sw = ch ^ ((slot & 7) << 4);
      g2l16(Eb + (size_t)ec * 128 + sw, (char*)El + slot * 128 + ch);
    }
  };

  // Q fragments straight from global (one-time, coalesced 16B/lane)
  const short8 aq0 = *(const short8*)&Qb[(size_t)(i0w + fr) * DH + fq * 8];
  const short8 aq1 = *(const short8*)&Qb[(size_t)(i0w + fr) * DH + 32 + fq * 8];

  float mrow[4], lrow[4];
  f32x4 accO[4];
#pragma unroll
  for (int r = 0; r < 4; r++) { mrow[r] = -3.0e38f; lrow[r] = 0.f; }
#pragma unroll
  for (int t = 0; t < 4; t++) accO[t] = fzero;

  f32x4 zzc = fzero;  // carried Er band fragment (prev f=4 -> next f=0)
  const int ksw = (fr & 7) << 4;

  for (int j0 = 0; j0 <= i0; j0 += 64) {
    // ---- stage this iter's K/V tile + fresh Er ring rows
    stageKV(j0);
    if (j0 == 0) stageEl(E0b, 4);            // full 128-row window
    else stageEl(E0b + j0 + 64, 2);          // 64 fresh rows
    __syncthreads();  // implicit vmcnt(0): staging landed

    // wave-uniform: highest unmasked t-subtile (always >= 0 here)
    int tmax = (i0w + 15 - j0) >> 4;
    if (tmax > 3) tmax = 3;

    // ---- S = Q K^T from swizzled LDS
    f32x4 sfr[4];
#pragma unroll
    for (int t = 0; t < 4; t++) sfr[t] = fzero;
    __builtin_amdgcn_s_setprio(1);
#pragma unroll
    for (int t = 0; t < 4; t++)
      if (t <= tmax) {
        const char* kr = (const char*)Kl + (t * 16 + fr) * 128;
        const short8 b0 = *(const short8*)(kr + ((fq * 16) ^ ksw));
        const short8 b1 = *(const short8*)(kr + ((64 + fq * 16) ^ ksw));
        f32x4 z = fzero;
        z = __builtin_amdgcn_mfma_f32_16x16x32_bf16(aq0, b0, z, 0, 0, 0);
        z = __builtin_amdgcn_mfma_f32_16x16x32_bf16(aq1, b1, z, 0, 0, 0);
        sfr[t] = z;
      }
    __builtin_amdgcn_s_setprio(0);

    // ---- banded QEr from the ring; f=0 carried when j0>0
    const int ebs = S_LEN - 16 - i0w + j0;  // band base (abs row, mult of 16)
    f32x4 zz[5];
#pragma unroll
    for (int f = 0; f < 5; f++) zz[f] = fzero;
    const int f0 = (j0 == 0) ? 0 : 1;
#pragma unroll
    for (int f = 0; f < 5; f++)
      if (f >= f0 && f <= tmax + 1) {
        const int slot = ((ebs + f * 16) & 127) + fr;  // no straddle
        const char* er = (const char*)El + slot * 128;
        const short8 b0 = *(const short8*)(er + ((fq * 16) ^ ksw));
        const short8 b1 = *(const short8*)(er + ((64 + fq * 16) ^ ksw));
        f32x4 z = fzero;
        z = __builtin_amdgcn_mfma_f32_16x16x32_bf16(aq0, b0, z, 0, 0, 0);
        z = __builtin_amdgcn_mfma_f32_16x16x32_bf16(aq1, b1, z, 0, 0, 0);
        zz[f] = z;
      }
    if (j0 > 0) zz[0] = zzc;
    zzc = zz[4];

    // ---- in-register skew gather: rel[t][r] = band col (15-row+fr)+16t
    float p[4][4];
#pragma unroll
    for (int r = 0; r < 4; r++) {
      const int row = fq * 4 + r;
      const int c = 15 - row + fr;           // 0..30
      const int src = (fq << 4) | (c & 15);  // same row-group, lane c&15
      float sh[5];
#pragma unroll
      for (int f = 0; f < 5; f++) sh[f] = __shfl(zz[f][r], src);
#pragma unroll
      for (int t = 0; t < 4; t++) {
        const float rel = (c < 16) ? sh[t] : sh[t + 1];
        float sv = (sfr[t][r] + rel) * 0.125f;
        const int jj = j0 + t * 16 + fr;
        const int ii = i0w + row;
        if (jj > ii) sv = -3.0e38f;
        p[t][r] = sv;
      }
    }

    // ---- online softmax (rows live in 16-lane groups, DPP reduce)
#pragma unroll
    for (int r = 0; r < 4; r++) {
      float rm = fmaxf(fmaxf(p[0][r], p[1][r]), fmaxf(p[2][r], p[3][r]));
      rm = grp16_max(rm);
      const float mnew = fmaxf(mrow[r], rm);
      const float alpha = __expf(mrow[r] - mnew);
      mrow[r] = mnew;
      float rs = 0.f;
#pragma unroll
      for (int t = 0; t < 4; t++) {
        const float e = __expf(p[t][r] - mnew);
        p[t][r] = e;
        rs += e;
      }
      rs = grp16_sum(rs);
      lrow[r] = lrow[r] * alpha + rs;
#pragma unroll
      for (int t = 0; t < 4; t++) accO[t][r] *= alpha;
    }

    // ---- P transpose, wave-private, XOR-swizzled (stride 64 u16)
#pragma unroll
    for (int t = 0; t < 4; t++)
#pragma unroll
      for (int r = 0; r < 4; r++)
        Pw[(fq * 4 + r) * 64 + (((t ^ fq) << 4) + fr)] = f2bf(p[t][r]);
    __builtin_amdgcn_s_waitcnt(0xC07F);  // lgkmcnt(0): own writes visible

    const int rsw = (fr >> 2) << 4;
    const short8 ap0 = *(const short8*)&Pw[fr * 64 + ((fq * 8) ^ rsw)];
    const short8 ap1 = *(const short8*)&Pw[fr * 64 + ((32 + fq * 8) ^ rsw)];

    // ---- O += P V from swizzled LDS
    __builtin_amdgcn_s_setprio(1);
#pragma unroll
    for (int t = 0; t < 4; t++) {
      const char* vr = (const char*)Vl + (t * 16 + fr) * 128;
      const short8 b0 = *(const short8*)(vr + ((fq * 16) ^ ksw));
      const short8 b1 = *(const short8*)(vr + ((64 + fq * 16) ^ ksw));
      accO[t] =
          __builtin_amdgcn_mfma_f32_16x16x32_bf16(ap0, b0, accO[t], 0, 0, 0);
      accO[t] =
          __builtin_amdgcn_mfma_f32_16x16x32_bf16(ap1, b1, accO[t], 0, 0, 0);
    }
    __builtin_amdgcn_s_setprio(0);

    __syncthreads();  // all reads done before next iter's staging overwrites
  }

  // ---- epilogue: O / l, write [B,S,D] fp32
#pragma unroll
  for (int r = 0; r < 4; r++) {
    const float inv = 1.f / lrow[r];
    const int s = i0w + fq * 4 + r;
#pragma unroll
    for (int t = 0; t < 4; t++) {
      const int d = t * 16 + fr;
      out[((size_t)b * S_LEN + s) * DM + h * DH + d] = accO[t][r] * inv;
    }
  }
}

extern "C" void kernel_launch(void* const* d_in, const int* in_sizes, int n_in,
                              void* d_out, int out_size, void* d_ws, size_t ws_size,
                              hipStream_t stream) {
  const float* x = (const float*)d_in[0];
  const float* Wq = (const float*)d_in[1];
  const float* bq = (const float*)d_in[2];
  const float* Wk = (const float*)d_in[3];
  const float* bk = (const float*)d_in[4];
  const float* Wv = (const float*)d_in[5];
  const float* bv = (const float*)d_in[6];
  const float* Er = (const float*)d_in[7];
  float* out = (float*)d_out;

  const size_t per = (size_t)NB * NH * S_LEN * DH;  // 4M elems
  u16* Qw = (u16*)d_ws;
  u16* Kw = Qw + per;
  u16* Vw = Kw + per;
  u16* xb = Vw + per;
  u16* Wqb = xb + per;
  u16* Wkb = Wqb + (size_t)DM * DM;
  u16* Wvb = Wkb + (size_t)DM * DM;
  u16* Erb = Wvb + (size_t)DM * DM;

  cvt_f32_bf16<<<3616, 256, 0, stream>>>(x, Wq, Wk, Wv, Er, xb, Wqb, Wkb, Wvb,
                                         Erb);
  dim3 g1(DM / 128, (NB * S_LEN) / 128, 3);
  qkv_gemm<<<g1, dim3(256), 0, stream>>>(xb, Wqb, bq, Wkb, bk, Wvb, bv, Qw, Kw,
                                         Vw);
  dim3 g2(16, NB * NH);
  attn<<<g2, dim3(256), 0, stream>>>(Qw, Kw, Vw, Erb, out);
}